// Round 3
// baseline (766.537 us; speedup 1.0000x reference)
//
#include <hip/hip_runtime.h>

// ---------------------------------------------------------------------------
// GNNEncoder: 4x SAGEConv + linear. R2:
//  - XCD-sliced CSR build: slice = blockIdx%8 (round-robin -> XCD), so adj
//    writes / cnt histogram stay in the local L2 -> no 16x writeback churn.
//  - mm_dual: t = h@Wl, u = h@Wr + b in one pass (h read once).
//  - gather_fused: out = relu(u + mean_j t[j]) -- float4 x 16 lanes/node,
//    int4-batched adj, no intermediate s buffer.
// ---------------------------------------------------------------------------

#define NSLICE 8

// sliced count: block (slice s, chunk k); LDS histogram over slice's nodes
__global__ __launch_bounds__(256) void count_sliced(
    const int* __restrict__ dst, int* __restrict__ cnt,
    int E, int N, int nps, int nchunk)
{
    extern __shared__ int hist[];             // nps ints
    const int slice = blockIdx.x & (NSLICE - 1);
    const int chunk = blockIdx.x / NSLICE;
    const int sbeg = slice * nps;
    const int send = min(sbeg + nps, N);
    const int nloc = send - sbeg;
    for (int i = threadIdx.x; i < nloc; i += 256) hist[i] = 0;
    __syncthreads();
    const int lo = (int)((long long)E * chunk / nchunk);
    const int hi = (int)((long long)E * (chunk + 1) / nchunk);
    for (int e = lo + threadIdx.x; e < hi; e += 256) {
        int d = dst[e];
        if (d >= sbeg && d < send) atomicAdd(&hist[d - sbeg], 1);
    }
    __syncthreads();
    for (int i = threadIdx.x; i < nloc; i += 256) {
        int v = hist[i];
        if (v) atomicAdd(&cnt[sbeg + i], v);
    }
}

// single block, 1024 threads: exclusive scan -> row_ptr, cursor, inv
__global__ __launch_bounds__(1024) void scan_kernel(
    const int* __restrict__ cnt, int* __restrict__ row_ptr,
    int* __restrict__ cursor, float* __restrict__ inv, int N)
{
    __shared__ int sums[1024];
    const int t = threadIdx.x;
    const int chunk = (N + 1023) >> 10;
    const int lo = t * chunk;
    const int hi = min(lo + chunk, N);
    int s = 0;
    for (int i = lo; i < hi; ++i) s += cnt[i];
    sums[t] = s;
    __syncthreads();
    for (int off = 1; off < 1024; off <<= 1) {
        int v = (t >= off) ? sums[t - off] : 0;
        __syncthreads();
        sums[t] += v;
        __syncthreads();
    }
    int base = (t == 0) ? 0 : sums[t - 1];
    for (int i = lo; i < hi; ++i) {
        int c = cnt[i];
        row_ptr[i] = base;
        cursor[i]  = base;
        inv[i] = 1.0f / (float)(c > 0 ? c : 1);
        base += c;
    }
    if (t == 0) row_ptr[N] = sums[1023];
}

// sliced fill: adj writes + cursor atomics stay XCD-local
__global__ __launch_bounds__(256) void fill_sliced(
    const int* __restrict__ src, const int* __restrict__ dst,
    int* __restrict__ cursor, int* __restrict__ adj,
    int E, int N, int nps, int nchunk)
{
    const int slice = blockIdx.x & (NSLICE - 1);
    const int chunk = blockIdx.x / NSLICE;
    const int sbeg = slice * nps;
    const int send = min(sbeg + nps, N);
    const int lo = (int)((long long)E * chunk / nchunk);
    const int hi = (int)((long long)E * (chunk + 1) / nchunk);
    for (int e = lo + threadIdx.x; e < hi; e += 256) {
        int d = dst[e];
        if (d >= sbeg && d < send) {
            int pos = atomicAdd(&cursor[d], 1);
            adj[pos] = src[e];
        }
    }
}

// pull aggregation fused with self-term: out = (relu)(u + inv * sum_j t[adj_j])
// 16 lanes per node, float4 per lane.
template<bool RELU>
__global__ __launch_bounds__(256) void gather_fused(
    const float* __restrict__ t, const int* __restrict__ adj,
    const int* __restrict__ row_ptr, const float* __restrict__ inv,
    const float* __restrict__ u, float* __restrict__ out, int N)
{
    const int node = (blockIdx.x * 256 + threadIdx.x) >> 4;
    const int l4 = (threadIdx.x & 15) * 4;
    if (node >= N) return;
    int j = row_ptr[node];
    const int end = row_ptr[node + 1];
    float ax = 0.f, ay = 0.f, az = 0.f, aw = 0.f;
    // align j to 4 for int4 adj loads
    while (j < end && (j & 3)) {
        const float4 v = *(const float4*)(t + (size_t)adj[j] * 64 + l4);
        ax += v.x; ay += v.y; az += v.z; aw += v.w;
        ++j;
    }
    for (; j + 4 <= end; j += 4) {
        const int4 nb = *(const int4*)(adj + j);
        const float4 v0 = *(const float4*)(t + (size_t)nb.x * 64 + l4);
        const float4 v1 = *(const float4*)(t + (size_t)nb.y * 64 + l4);
        const float4 v2 = *(const float4*)(t + (size_t)nb.z * 64 + l4);
        const float4 v3 = *(const float4*)(t + (size_t)nb.w * 64 + l4);
        ax += (v0.x + v1.x) + (v2.x + v3.x);
        ay += (v0.y + v1.y) + (v2.y + v3.y);
        az += (v0.z + v1.z) + (v2.z + v3.z);
        aw += (v0.w + v1.w) + (v2.w + v3.w);
    }
    for (; j < end; ++j) {
        const float4 v = *(const float4*)(t + (size_t)adj[j] * 64 + l4);
        ax += v.x; ay += v.y; az += v.z; aw += v.w;
    }
    const float vi = inv[node];
    const float4 uu = *(const float4*)(u + (size_t)node * 64 + l4);
    float4 o;
    o.x = uu.x + ax * vi;
    o.y = uu.y + ay * vi;
    o.z = uu.z + az * vi;
    o.w = uu.w + aw * vi;
    if (RELU) {
        o.x = fmaxf(o.x, 0.f); o.y = fmaxf(o.y, 0.f);
        o.z = fmaxf(o.z, 0.f); o.w = fmaxf(o.w, 0.f);
    }
    *(float4*)(out + (size_t)node * 64 + l4) = o;
}

// T[M,64] = A[M,K]@Wl ; U[M,64] = A[M,K]@Wr + b   (K in {64,128}, chunked 64)
template<int K>
__global__ __launch_bounds__(256) void mm_dual(
    const float* __restrict__ A, const float* __restrict__ Wl,
    const float* __restrict__ Wr, const float* __restrict__ bias,
    float* __restrict__ T, float* __restrict__ U, int M)
{
    __shared__ float As[64][68];
    __shared__ float Wls[64 * 64];
    __shared__ float Wrs[64 * 64];
    const int tid  = threadIdx.x;
    const int row0 = blockIdx.x * 64;
    const int tx = tid & 15, ty = tid >> 4;
    float accT[4][4] = {{0.f}}, accU[4][4] = {{0.f}};

    for (int kc = 0; kc < K; kc += 64) {
        for (int i = tid * 4; i < 64 * 64; i += 1024) {
            int r = i >> 6, c = i & 63;
            int gr = row0 + r;
            float4 v = make_float4(0.f, 0.f, 0.f, 0.f);
            if (gr < M) v = *(const float4*)&A[(size_t)gr * K + kc + c];
            *(float4*)&As[r][c] = v;
        }
        for (int i = tid * 4; i < 64 * 64; i += 1024) {
            *(float4*)&Wls[i] = *(const float4*)&Wl[kc * 64 + i];
            *(float4*)&Wrs[i] = *(const float4*)&Wr[kc * 64 + i];
        }
        __syncthreads();
        #pragma unroll 4
        for (int kk = 0; kk < 64; ++kk) {
            float a[4];
            #pragma unroll
            for (int r = 0; r < 4; ++r) a[r] = As[ty * 4 + r][kk];
            float bl[4], br[4];
            #pragma unroll
            for (int c = 0; c < 4; ++c) {
                bl[c] = Wls[kk * 64 + tx * 4 + c];
                br[c] = Wrs[kk * 64 + tx * 4 + c];
            }
            #pragma unroll
            for (int r = 0; r < 4; ++r)
                #pragma unroll
                for (int c = 0; c < 4; ++c) {
                    accT[r][c] += a[r] * bl[c];
                    accU[r][c] += a[r] * br[c];
                }
        }
        __syncthreads();
    }

    const float4 bv = *(const float4*)&bias[tx * 4];
    #pragma unroll
    for (int r = 0; r < 4; ++r) {
        int gr = row0 + ty * 4 + r;
        if (gr >= M) continue;
        *(float4*)&T[(size_t)gr * 64 + tx * 4] =
            make_float4(accT[r][0], accT[r][1], accT[r][2], accT[r][3]);
        *(float4*)&U[(size_t)gr * 64 + tx * 4] =
            make_float4(accU[r][0] + bv.x, accU[r][1] + bv.y,
                        accU[r][2] + bv.z, accU[r][3] + bv.w);
    }
}

// final linear: C[M,32] = A[M,64]@W + b
__global__ __launch_bounds__(256) void mm_lin(
    const float* __restrict__ A, const float* __restrict__ W,
    const float* __restrict__ bias, float* __restrict__ C, int M)
{
    __shared__ float As[64][68];
    __shared__ float Ws[64 * 32];
    const int tid  = threadIdx.x;
    const int row0 = blockIdx.x * 64;

    for (int i = tid * 4; i < 64 * 32; i += 1024) {
        *(float4*)&Ws[i] = *(const float4*)&W[i];
    }
    for (int i = tid * 4; i < 64 * 64; i += 1024) {
        int r = i >> 6, c = i & 63;
        int gr = row0 + r;
        float4 v = make_float4(0.f, 0.f, 0.f, 0.f);
        if (gr < M) v = *(const float4*)&A[(size_t)gr * 64 + c];
        *(float4*)&As[r][c] = v;
    }
    __syncthreads();

    const int tx = tid & 15, ty = tid >> 4;
    float acc[4][2] = {{0.f}};
    #pragma unroll 4
    for (int kk = 0; kk < 64; ++kk) {
        float a[4];
        #pragma unroll
        for (int r = 0; r < 4; ++r) a[r] = As[ty * 4 + r][kk];
        float b0 = Ws[kk * 32 + tx * 2];
        float b1 = Ws[kk * 32 + tx * 2 + 1];
        #pragma unroll
        for (int r = 0; r < 4; ++r) {
            acc[r][0] += a[r] * b0;
            acc[r][1] += a[r] * b1;
        }
    }
    #pragma unroll
    for (int r = 0; r < 4; ++r) {
        int gr = row0 + ty * 4 + r;
        if (gr >= M) continue;
        float2 o = make_float2(acc[r][0] + bias[tx * 2],
                               acc[r][1] + bias[tx * 2 + 1]);
        *(float2*)&C[(size_t)gr * 32 + tx * 2] = o;
    }
}

extern "C" void kernel_launch(void* const* d_in, const int* in_sizes, int n_in,
                              void* d_out, int out_size, void* d_ws, size_t ws_size,
                              hipStream_t stream) {
    const float* x     = (const float*)d_in[0];
    const int*   ei    = (const int*)  d_in[1];
    const float* W1a_l = (const float*)d_in[2];
    const float* b1a   = (const float*)d_in[3];
    const float* W1a_r = (const float*)d_in[4];
    const float* W1b_l = (const float*)d_in[5];
    const float* b1b   = (const float*)d_in[6];
    const float* W1b_r = (const float*)d_in[7];
    const float* W2a_l = (const float*)d_in[8];
    const float* b2a   = (const float*)d_in[9];
    const float* W2a_r = (const float*)d_in[10];
    const float* W2b_l = (const float*)d_in[11];
    const float* b2b   = (const float*)d_in[12];
    const float* W2b_r = (const float*)d_in[13];
    const float* Wlin  = (const float*)d_in[14];
    const float* blin  = (const float*)d_in[15];

    const int N = in_sizes[0] / 128;
    const int E = in_sizes[1] / 2;
    const int* src = ei;
    const int* dst = ei + E;
    const int nps = (N + NSLICE - 1) / NSLICE;    // nodes per slice

    size_t o = 0;
    auto take = [&](size_t bytes) -> void* {
        void* p = (char*)d_ws + o;
        o += (bytes + 255) & ~(size_t)255;
        return p;
    };
    int*   cnt     = (int*)  take((size_t)N * 4);
    int*   row_ptr = (int*)  take((size_t)(N + 1) * 4);
    int*   cursor  = (int*)  take((size_t)N * 4);
    float* inv     = (float*)take((size_t)N * 4);
    int*   adj     = (int*)  take((size_t)E * 4);
    float* t       = (float*)take((size_t)N * 64 * 4);
    float* u       = (float*)take((size_t)N * 64 * 4);
    float* hA      = (float*)take((size_t)N * 64 * 4);
    float* hB      = (float*)take((size_t)N * 64 * 4);
    (void)ws_size; (void)n_in; (void)out_size;

    const int mb = (N + 63) / 64;                 // mm blocks
    const int gb = (N * 16 + 255) / 256;          // gather blocks (16 ln/node)

    // ---- build CSR (XCD-sliced) ----
    const int cnt_chunks  = 8;                    // 64 blocks, LDS hist
    const int fill_chunks = 96;                   // 768 blocks
    hipMemsetAsync(cnt, 0, (size_t)N * 4, stream);
    count_sliced<<<NSLICE * cnt_chunks, 256, nps * 4, stream>>>(
        dst, cnt, E, N, nps, cnt_chunks);
    scan_kernel<<<1, 1024, 0, stream>>>(cnt, row_ptr, cursor, inv, N);
    fill_sliced<<<NSLICE * fill_chunks, 256, 0, stream>>>(
        src, dst, cursor, adj, E, N, nps, fill_chunks);

    // ---- layer 1a: x[*,128] -> hA, relu ----
    mm_dual<128><<<mb, 256, 0, stream>>>(x, W1a_l, W1a_r, b1a, t, u, N);
    gather_fused<true><<<gb, 256, 0, stream>>>(t, adj, row_ptr, inv, u, hA, N);
    // ---- layer 1b: hA -> hB, relu ----
    mm_dual<64><<<mb, 256, 0, stream>>>(hA, W1b_l, W1b_r, b1b, t, u, N);
    gather_fused<true><<<gb, 256, 0, stream>>>(t, adj, row_ptr, inv, u, hB, N);
    // ---- layer 2a: hB -> hA, relu ----
    mm_dual<64><<<mb, 256, 0, stream>>>(hB, W2a_l, W2a_r, b2a, t, u, N);
    gather_fused<true><<<gb, 256, 0, stream>>>(t, adj, row_ptr, inv, u, hA, N);
    // ---- layer 2b: hA -> hB, no relu ----
    mm_dual<64><<<mb, 256, 0, stream>>>(hA, W2b_l, W2b_r, b2b, t, u, N);
    gather_fused<false><<<gb, 256, 0, stream>>>(t, adj, row_ptr, inv, u, hB, N);
    // ---- final linear ----
    mm_lin<<<mb, 256, 0, stream>>>(hB, Wlin, blin, (float*)d_out, N);
}

// Round 4
// 589.982 us; speedup vs baseline: 1.2993x; 1.2993x over previous
//
#include <hip/hip_runtime.h>

// ---------------------------------------------------------------------------
// GNNEncoder: 4x SAGEConv + linear. R3:
//  - count: plain global atomics (R2's 64-block LDS-hist version was 300us at
//    2.7% occupancy -- reverted to R1 scheme that never hit top-5).
//  - fill: XCD-sliced (slice = blockIdx%8) -- kept from R2, adj writes merge
//    in the local L2 instead of 16x line-writeback churn.
//  - gather: one WAVE per node, 4-neighbor groups x 16 dim-lanes, float4.
//    No degree divergence inside a wave; cross-group shfl_xor reduce.
//  - mm_dual: t = h@Wl, u = h@Wr + b in one pass; gather adds mean + relu.
// ---------------------------------------------------------------------------

#define NSLICE 8

__global__ void count_kernel(const int* __restrict__ dst, int* __restrict__ cnt, int E) {
    int e = blockIdx.x * blockDim.x + threadIdx.x;
    if (e < E) atomicAdd(&cnt[dst[e]], 1);
}

// single block, 1024 threads: exclusive scan -> row_ptr, cursor, inv
__global__ __launch_bounds__(1024) void scan_kernel(
    const int* __restrict__ cnt, int* __restrict__ row_ptr,
    int* __restrict__ cursor, float* __restrict__ inv, int N)
{
    __shared__ int sums[1024];
    const int t = threadIdx.x;
    const int chunk = (N + 1023) >> 10;
    const int lo = t * chunk;
    const int hi = min(lo + chunk, N);
    int s = 0;
    for (int i = lo; i < hi; ++i) s += cnt[i];
    sums[t] = s;
    __syncthreads();
    for (int off = 1; off < 1024; off <<= 1) {
        int v = (t >= off) ? sums[t - off] : 0;
        __syncthreads();
        sums[t] += v;
        __syncthreads();
    }
    int base = (t == 0) ? 0 : sums[t - 1];
    for (int i = lo; i < hi; ++i) {
        int c = cnt[i];
        row_ptr[i] = base;
        cursor[i]  = base;
        inv[i] = 1.0f / (float)(c > 0 ? c : 1);
        base += c;
    }
    if (t == 0) row_ptr[N] = sums[1023];
}

// sliced fill: adj writes + cursor atomics stay XCD-local
__global__ __launch_bounds__(256) void fill_sliced(
    const int* __restrict__ src, const int* __restrict__ dst,
    int* __restrict__ cursor, int* __restrict__ adj,
    int E, int N, int nps, int nchunk)
{
    const int slice = blockIdx.x & (NSLICE - 1);
    const int chunk = blockIdx.x / NSLICE;
    const int sbeg = slice * nps;
    const int send = min(sbeg + nps, N);
    const int lo = (int)((long long)E * chunk / nchunk);
    const int hi = (int)((long long)E * (chunk + 1) / nchunk);
    for (int e = lo + threadIdx.x; e < hi; e += 256) {
        int d = dst[e];
        if (d >= sbeg && d < send) {
            int pos = atomicAdd(&cursor[d], 1);
            adj[pos] = src[e];
        }
    }
}

// pull aggregation fused with self-term: out = (relu)(u + inv * sum_j t[adj_j])
// one wave per node: 4 neighbor-groups x 16 dim-lanes, float4 per lane.
template<bool RELU>
__global__ __launch_bounds__(256) void gather_fused(
    const float* __restrict__ t, const int* __restrict__ adj,
    const int* __restrict__ row_ptr, const float* __restrict__ inv,
    const float* __restrict__ u, float* __restrict__ out, int N)
{
    const int node = (blockIdx.x * 256 + threadIdx.x) >> 6;
    const int lane = threadIdx.x & 63;
    const int grp  = lane >> 4;          // 0..3: which neighbor in the quad
    const int l4   = (lane & 15) * 4;    // dim offset
    if (node >= N) return;
    const int beg = row_ptr[node], end = row_ptr[node + 1];
    float ax = 0.f, ay = 0.f, az = 0.f, aw = 0.f;
    int j = beg + grp;
    for (; j + 4 < end; j += 8) {        // 2x unrolled: j and j+4
        const int n0 = adj[j], n1 = adj[j + 4];
        const float4 v0 = *(const float4*)(t + (size_t)n0 * 64 + l4);
        const float4 v1 = *(const float4*)(t + (size_t)n1 * 64 + l4);
        ax += v0.x + v1.x; ay += v0.y + v1.y;
        az += v0.z + v1.z; aw += v0.w + v1.w;
    }
    if (j < end) {
        const float4 v = *(const float4*)(t + (size_t)adj[j] * 64 + l4);
        ax += v.x; ay += v.y; az += v.z; aw += v.w;
    }
    // reduce across the 4 groups (lane bits 4 and 5)
    ax += __shfl_xor(ax, 16); ay += __shfl_xor(ay, 16);
    az += __shfl_xor(az, 16); aw += __shfl_xor(aw, 16);
    ax += __shfl_xor(ax, 32); ay += __shfl_xor(ay, 32);
    az += __shfl_xor(az, 32); aw += __shfl_xor(aw, 32);
    if (grp == 0) {
        const float vi = inv[node];
        const float4 uu = *(const float4*)(u + (size_t)node * 64 + l4);
        float4 o;
        o.x = uu.x + ax * vi;
        o.y = uu.y + ay * vi;
        o.z = uu.z + az * vi;
        o.w = uu.w + aw * vi;
        if (RELU) {
            o.x = fmaxf(o.x, 0.f); o.y = fmaxf(o.y, 0.f);
            o.z = fmaxf(o.z, 0.f); o.w = fmaxf(o.w, 0.f);
        }
        *(float4*)(out + (size_t)node * 64 + l4) = o;
    }
}

// T[M,64] = A[M,K]@Wl ; U[M,64] = A[M,K]@Wr + b   (K in {64,128}, chunked 64)
template<int K>
__global__ __launch_bounds__(256) void mm_dual(
    const float* __restrict__ A, const float* __restrict__ Wl,
    const float* __restrict__ Wr, const float* __restrict__ bias,
    float* __restrict__ T, float* __restrict__ U, int M)
{
    __shared__ float As[64][68];
    __shared__ float Wls[64 * 64];
    __shared__ float Wrs[64 * 64];
    const int tid  = threadIdx.x;
    const int row0 = blockIdx.x * 64;
    const int tx = tid & 15, ty = tid >> 4;
    float accT[4][4] = {{0.f}}, accU[4][4] = {{0.f}};

    for (int kc = 0; kc < K; kc += 64) {
        for (int i = tid * 4; i < 64 * 64; i += 1024) {
            int r = i >> 6, c = i & 63;
            int gr = row0 + r;
            float4 v = make_float4(0.f, 0.f, 0.f, 0.f);
            if (gr < M) v = *(const float4*)&A[(size_t)gr * K + kc + c];
            *(float4*)&As[r][c] = v;
        }
        for (int i = tid * 4; i < 64 * 64; i += 1024) {
            *(float4*)&Wls[i] = *(const float4*)&Wl[kc * 64 + i];
            *(float4*)&Wrs[i] = *(const float4*)&Wr[kc * 64 + i];
        }
        __syncthreads();
        #pragma unroll 4
        for (int kk = 0; kk < 64; ++kk) {
            float a[4];
            #pragma unroll
            for (int r = 0; r < 4; ++r) a[r] = As[ty * 4 + r][kk];
            float bl[4], br[4];
            #pragma unroll
            for (int c = 0; c < 4; ++c) {
                bl[c] = Wls[kk * 64 + tx * 4 + c];
                br[c] = Wrs[kk * 64 + tx * 4 + c];
            }
            #pragma unroll
            for (int r = 0; r < 4; ++r)
                #pragma unroll
                for (int c = 0; c < 4; ++c) {
                    accT[r][c] += a[r] * bl[c];
                    accU[r][c] += a[r] * br[c];
                }
        }
        __syncthreads();
    }

    const float4 bv = *(const float4*)&bias[tx * 4];
    #pragma unroll
    for (int r = 0; r < 4; ++r) {
        int gr = row0 + ty * 4 + r;
        if (gr >= M) continue;
        *(float4*)&T[(size_t)gr * 64 + tx * 4] =
            make_float4(accT[r][0], accT[r][1], accT[r][2], accT[r][3]);
        *(float4*)&U[(size_t)gr * 64 + tx * 4] =
            make_float4(accU[r][0] + bv.x, accU[r][1] + bv.y,
                        accU[r][2] + bv.z, accU[r][3] + bv.w);
    }
}

// final linear: C[M,32] = A[M,64]@W + b
__global__ __launch_bounds__(256) void mm_lin(
    const float* __restrict__ A, const float* __restrict__ W,
    const float* __restrict__ bias, float* __restrict__ C, int M)
{
    __shared__ float As[64][68];
    __shared__ float Ws[64 * 32];
    const int tid  = threadIdx.x;
    const int row0 = blockIdx.x * 64;

    for (int i = tid * 4; i < 64 * 32; i += 1024) {
        *(float4*)&Ws[i] = *(const float4*)&W[i];
    }
    for (int i = tid * 4; i < 64 * 64; i += 1024) {
        int r = i >> 6, c = i & 63;
        int gr = row0 + r;
        float4 v = make_float4(0.f, 0.f, 0.f, 0.f);
        if (gr < M) v = *(const float4*)&A[(size_t)gr * 64 + c];
        *(float4*)&As[r][c] = v;
    }
    __syncthreads();

    const int tx = tid & 15, ty = tid >> 4;
    float acc[4][2] = {{0.f}};
    #pragma unroll 4
    for (int kk = 0; kk < 64; ++kk) {
        float a[4];
        #pragma unroll
        for (int r = 0; r < 4; ++r) a[r] = As[ty * 4 + r][kk];
        float b0 = Ws[kk * 32 + tx * 2];
        float b1 = Ws[kk * 32 + tx * 2 + 1];
        #pragma unroll
        for (int r = 0; r < 4; ++r) {
            acc[r][0] += a[r] * b0;
            acc[r][1] += a[r] * b1;
        }
    }
    #pragma unroll
    for (int r = 0; r < 4; ++r) {
        int gr = row0 + ty * 4 + r;
        if (gr >= M) continue;
        float2 o = make_float2(acc[r][0] + bias[tx * 2],
                               acc[r][1] + bias[tx * 2 + 1]);
        *(float2*)&C[(size_t)gr * 32 + tx * 2] = o;
    }
}

extern "C" void kernel_launch(void* const* d_in, const int* in_sizes, int n_in,
                              void* d_out, int out_size, void* d_ws, size_t ws_size,
                              hipStream_t stream) {
    const float* x     = (const float*)d_in[0];
    const int*   ei    = (const int*)  d_in[1];
    const float* W1a_l = (const float*)d_in[2];
    const float* b1a   = (const float*)d_in[3];
    const float* W1a_r = (const float*)d_in[4];
    const float* W1b_l = (const float*)d_in[5];
    const float* b1b   = (const float*)d_in[6];
    const float* W1b_r = (const float*)d_in[7];
    const float* W2a_l = (const float*)d_in[8];
    const float* b2a   = (const float*)d_in[9];
    const float* W2a_r = (const float*)d_in[10];
    const float* W2b_l = (const float*)d_in[11];
    const float* b2b   = (const float*)d_in[12];
    const float* W2b_r = (const float*)d_in[13];
    const float* Wlin  = (const float*)d_in[14];
    const float* blin  = (const float*)d_in[15];

    const int N = in_sizes[0] / 128;
    const int E = in_sizes[1] / 2;
    const int* src = ei;
    const int* dst = ei + E;
    const int nps = (N + NSLICE - 1) / NSLICE;    // nodes per slice

    size_t o = 0;
    auto take = [&](size_t bytes) -> void* {
        void* p = (char*)d_ws + o;
        o += (bytes + 255) & ~(size_t)255;
        return p;
    };
    int*   cnt     = (int*)  take((size_t)N * 4);
    int*   row_ptr = (int*)  take((size_t)(N + 1) * 4);
    int*   cursor  = (int*)  take((size_t)N * 4);
    float* inv     = (float*)take((size_t)N * 4);
    int*   adj     = (int*)  take((size_t)E * 4);
    float* t       = (float*)take((size_t)N * 64 * 4);
    float* u       = (float*)take((size_t)N * 64 * 4);
    float* hA      = (float*)take((size_t)N * 64 * 4);
    float* hB      = (float*)take((size_t)N * 64 * 4);
    (void)ws_size; (void)n_in; (void)out_size;

    const int mb = (N + 63) / 64;                 // mm blocks
    const int gb = (N * 64 + 255) / 256;          // gather blocks (wave/node)
    const int eb = (E + 255) / 256;

    // ---- build CSR ----
    const int fill_chunks = 96;                   // 768 blocks
    hipMemsetAsync(cnt, 0, (size_t)N * 4, stream);
    count_kernel<<<eb, 256, 0, stream>>>(dst, cnt, E);
    scan_kernel<<<1, 1024, 0, stream>>>(cnt, row_ptr, cursor, inv, N);
    fill_sliced<<<NSLICE * fill_chunks, 256, 0, stream>>>(
        src, dst, cursor, adj, E, N, nps, fill_chunks);

    // ---- layer 1a: x[*,128] -> hA, relu ----
    mm_dual<128><<<mb, 256, 0, stream>>>(x, W1a_l, W1a_r, b1a, t, u, N);
    gather_fused<true><<<gb, 256, 0, stream>>>(t, adj, row_ptr, inv, u, hA, N);
    // ---- layer 1b: hA -> hB, relu ----
    mm_dual<64><<<mb, 256, 0, stream>>>(hA, W1b_l, W1b_r, b1b, t, u, N);
    gather_fused<true><<<gb, 256, 0, stream>>>(t, adj, row_ptr, inv, u, hB, N);
    // ---- layer 2a: hB -> hA, relu ----
    mm_dual<64><<<mb, 256, 0, stream>>>(hB, W2a_l, W2a_r, b2a, t, u, N);
    gather_fused<true><<<gb, 256, 0, stream>>>(t, adj, row_ptr, inv, u, hA, N);
    // ---- layer 2b: hA -> hB, no relu ----
    mm_dual<64><<<mb, 256, 0, stream>>>(hA, W2b_l, W2b_r, b2b, t, u, N);
    gather_fused<false><<<gb, 256, 0, stream>>>(t, adj, row_ptr, inv, u, hB, N);
    // ---- final linear ----
    mm_lin<<<mb, 256, 0, stream>>>(hB, Wlin, blin, (float*)d_out, N);
}

// Round 5
// 469.354 us; speedup vs baseline: 1.6332x; 1.2570x over previous
//
#include <hip/hip_runtime.h>

// ---------------------------------------------------------------------------
// GNNEncoder: 4x SAGEConv + linear. R4:
//  - scan: 3-phase multi-block scan (25 blocks) replaces single-block scan
//    that ran at 0.14% occupancy for 136us.
//  - count: plain global atomics; fill: XCD-sliced (both proven sub-top-5).
//  - gather: wave per node, 4-neighbor groups x 16 dim-lanes, float4, fused
//    self-term + bias + relu.
//  - mm_dual: t = h@Wl, u = h@Wr + b in one pass.
// ---------------------------------------------------------------------------

#define NSLICE 8
#define SCAN_NPB 2048   // nodes per scan block (256 threads x 8)

__global__ void count_kernel(const int* __restrict__ dst, int* __restrict__ cnt, int E) {
    int e = blockIdx.x * blockDim.x + threadIdx.x;
    if (e < E) atomicAdd(&cnt[dst[e]], 1);
}

// phase 1: per-block sums of cnt
__global__ __launch_bounds__(256) void scan_partial(
    const int* __restrict__ cnt, int* __restrict__ partial, int N)
{
    __shared__ int red[256];
    const int base = blockIdx.x * SCAN_NPB + threadIdx.x * 8;
    int s = 0;
    #pragma unroll
    for (int k = 0; k < 8; ++k) {
        int i = base + k;
        if (i < N) s += cnt[i];
    }
    red[threadIdx.x] = s;
    __syncthreads();
    for (int off = 128; off > 0; off >>= 1) {
        if (threadIdx.x < off) red[threadIdx.x] += red[threadIdx.x + off];
        __syncthreads();
    }
    if (threadIdx.x == 0) partial[blockIdx.x] = red[0];
}

// phase 2: single wave exclusive-scans nb (<=64) partials in place
__global__ __launch_bounds__(64) void scan_partial_scan(int* __restrict__ partial, int nb)
{
    const int lane = threadIdx.x;
    int v = (lane < nb) ? partial[lane] : 0;
    int incl = v;
    #pragma unroll
    for (int off = 1; off < 64; off <<= 1) {
        int o = __shfl_up(incl, off);
        if (lane >= off) incl += o;
    }
    if (lane < nb) partial[lane] = incl - v;   // exclusive
}

// phase 3: local scan + offset -> row_ptr, cursor, inv; last node writes row_ptr[N]
__global__ __launch_bounds__(256) void scan_final(
    const int* __restrict__ cnt, const int* __restrict__ partial,
    int* __restrict__ row_ptr, int* __restrict__ cursor,
    float* __restrict__ inv, int N)
{
    __shared__ int sums[256];
    const int tid = threadIdx.x;
    const int base = blockIdx.x * SCAN_NPB + tid * 8;
    int c[8], p = 0;
    #pragma unroll
    for (int k = 0; k < 8; ++k) {
        int i = base + k;
        c[k] = (i < N) ? cnt[i] : 0;
        p += c[k];
    }
    sums[tid] = p;
    __syncthreads();
    // Hillis-Steele inclusive scan over thread sums
    for (int off = 1; off < 256; off <<= 1) {
        int v = (tid >= off) ? sums[tid - off] : 0;
        __syncthreads();
        sums[tid] += v;
        __syncthreads();
    }
    int run = partial[blockIdx.x] + ((tid > 0) ? sums[tid - 1] : 0);
    #pragma unroll
    for (int k = 0; k < 8; ++k) {
        int i = base + k;
        if (i < N) {
            row_ptr[i] = run;
            cursor[i]  = run;
            inv[i] = 1.0f / (float)(c[k] > 0 ? c[k] : 1);
            run += c[k];
            if (i == N - 1) row_ptr[N] = run;
        }
    }
}

// sliced fill: adj writes + cursor atomics stay XCD-local
__global__ __launch_bounds__(256) void fill_sliced(
    const int* __restrict__ src, const int* __restrict__ dst,
    int* __restrict__ cursor, int* __restrict__ adj,
    int E, int N, int nps, int nchunk)
{
    const int slice = blockIdx.x & (NSLICE - 1);
    const int chunk = blockIdx.x / NSLICE;
    const int sbeg = slice * nps;
    const int send = min(sbeg + nps, N);
    const int lo = (int)((long long)E * chunk / nchunk);
    const int hi = (int)((long long)E * (chunk + 1) / nchunk);
    for (int e = lo + threadIdx.x; e < hi; e += 256) {
        int d = dst[e];
        if (d >= sbeg && d < send) {
            int pos = atomicAdd(&cursor[d], 1);
            adj[pos] = src[e];
        }
    }
}

// pull aggregation fused with self-term: out = (relu)(u + inv * sum_j t[adj_j])
// one wave per node: 4 neighbor-groups x 16 dim-lanes, float4 per lane.
template<bool RELU>
__global__ __launch_bounds__(256) void gather_fused(
    const float* __restrict__ t, const int* __restrict__ adj,
    const int* __restrict__ row_ptr, const float* __restrict__ inv,
    const float* __restrict__ u, float* __restrict__ out, int N)
{
    const int node = (blockIdx.x * 256 + threadIdx.x) >> 6;
    const int lane = threadIdx.x & 63;
    const int grp  = lane >> 4;          // 0..3: which neighbor in the quad
    const int l4   = (lane & 15) * 4;    // dim offset
    if (node >= N) return;
    const int beg = row_ptr[node], end = row_ptr[node + 1];
    float ax = 0.f, ay = 0.f, az = 0.f, aw = 0.f;
    int j = beg + grp;
    for (; j + 4 < end; j += 8) {        // 2x unrolled: j and j+4
        const int n0 = adj[j], n1 = adj[j + 4];
        const float4 v0 = *(const float4*)(t + (size_t)n0 * 64 + l4);
        const float4 v1 = *(const float4*)(t + (size_t)n1 * 64 + l4);
        ax += v0.x + v1.x; ay += v0.y + v1.y;
        az += v0.z + v1.z; aw += v0.w + v1.w;
    }
    if (j < end) {
        const float4 v = *(const float4*)(t + (size_t)adj[j] * 64 + l4);
        ax += v.x; ay += v.y; az += v.z; aw += v.w;
    }
    // reduce across the 4 groups (lane bits 4 and 5)
    ax += __shfl_xor(ax, 16); ay += __shfl_xor(ay, 16);
    az += __shfl_xor(az, 16); aw += __shfl_xor(aw, 16);
    ax += __shfl_xor(ax, 32); ay += __shfl_xor(ay, 32);
    az += __shfl_xor(az, 32); aw += __shfl_xor(aw, 32);
    if (grp == 0) {
        const float vi = inv[node];
        const float4 uu = *(const float4*)(u + (size_t)node * 64 + l4);
        float4 o;
        o.x = uu.x + ax * vi;
        o.y = uu.y + ay * vi;
        o.z = uu.z + az * vi;
        o.w = uu.w + aw * vi;
        if (RELU) {
            o.x = fmaxf(o.x, 0.f); o.y = fmaxf(o.y, 0.f);
            o.z = fmaxf(o.z, 0.f); o.w = fmaxf(o.w, 0.f);
        }
        *(float4*)(out + (size_t)node * 64 + l4) = o;
    }
}

// T[M,64] = A[M,K]@Wl ; U[M,64] = A[M,K]@Wr + b   (K in {64,128}, chunked 64)
template<int K>
__global__ __launch_bounds__(256) void mm_dual(
    const float* __restrict__ A, const float* __restrict__ Wl,
    const float* __restrict__ Wr, const float* __restrict__ bias,
    float* __restrict__ T, float* __restrict__ U, int M)
{
    __shared__ float As[64][68];
    __shared__ float Wls[64 * 64];
    __shared__ float Wrs[64 * 64];
    const int tid  = threadIdx.x;
    const int row0 = blockIdx.x * 64;
    const int tx = tid & 15, ty = tid >> 4;
    float accT[4][4] = {{0.f}}, accU[4][4] = {{0.f}};

    for (int kc = 0; kc < K; kc += 64) {
        for (int i = tid * 4; i < 64 * 64; i += 1024) {
            int r = i >> 6, c = i & 63;
            int gr = row0 + r;
            float4 v = make_float4(0.f, 0.f, 0.f, 0.f);
            if (gr < M) v = *(const float4*)&A[(size_t)gr * K + kc + c];
            *(float4*)&As[r][c] = v;
        }
        for (int i = tid * 4; i < 64 * 64; i += 1024) {
            *(float4*)&Wls[i] = *(const float4*)&Wl[kc * 64 + i];
            *(float4*)&Wrs[i] = *(const float4*)&Wr[kc * 64 + i];
        }
        __syncthreads();
        #pragma unroll 4
        for (int kk = 0; kk < 64; ++kk) {
            float a[4];
            #pragma unroll
            for (int r = 0; r < 4; ++r) a[r] = As[ty * 4 + r][kk];
            float bl[4], br[4];
            #pragma unroll
            for (int c = 0; c < 4; ++c) {
                bl[c] = Wls[kk * 64 + tx * 4 + c];
                br[c] = Wrs[kk * 64 + tx * 4 + c];
            }
            #pragma unroll
            for (int r = 0; r < 4; ++r)
                #pragma unroll
                for (int c = 0; c < 4; ++c) {
                    accT[r][c] += a[r] * bl[c];
                    accU[r][c] += a[r] * br[c];
                }
        }
        __syncthreads();
    }

    const float4 bv = *(const float4*)&bias[tx * 4];
    #pragma unroll
    for (int r = 0; r < 4; ++r) {
        int gr = row0 + ty * 4 + r;
        if (gr >= M) continue;
        *(float4*)&T[(size_t)gr * 64 + tx * 4] =
            make_float4(accT[r][0], accT[r][1], accT[r][2], accT[r][3]);
        *(float4*)&U[(size_t)gr * 64 + tx * 4] =
            make_float4(accU[r][0] + bv.x, accU[r][1] + bv.y,
                        accU[r][2] + bv.z, accU[r][3] + bv.w);
    }
}

// final linear: C[M,32] = A[M,64]@W + b
__global__ __launch_bounds__(256) void mm_lin(
    const float* __restrict__ A, const float* __restrict__ W,
    const float* __restrict__ bias, float* __restrict__ C, int M)
{
    __shared__ float As[64][68];
    __shared__ float Ws[64 * 32];
    const int tid  = threadIdx.x;
    const int row0 = blockIdx.x * 64;

    for (int i = tid * 4; i < 64 * 32; i += 1024) {
        *(float4*)&Ws[i] = *(const float4*)&W[i];
    }
    for (int i = tid * 4; i < 64 * 64; i += 1024) {
        int r = i >> 6, c = i & 63;
        int gr = row0 + r;
        float4 v = make_float4(0.f, 0.f, 0.f, 0.f);
        if (gr < M) v = *(const float4*)&A[(size_t)gr * 64 + c];
        *(float4*)&As[r][c] = v;
    }
    __syncthreads();

    const int tx = tid & 15, ty = tid >> 4;
    float acc[4][2] = {{0.f}};
    #pragma unroll 4
    for (int kk = 0; kk < 64; ++kk) {
        float a[4];
        #pragma unroll
        for (int r = 0; r < 4; ++r) a[r] = As[ty * 4 + r][kk];
        float b0 = Ws[kk * 32 + tx * 2];
        float b1 = Ws[kk * 32 + tx * 2 + 1];
        #pragma unroll
        for (int r = 0; r < 4; ++r) {
            acc[r][0] += a[r] * b0;
            acc[r][1] += a[r] * b1;
        }
    }
    #pragma unroll
    for (int r = 0; r < 4; ++r) {
        int gr = row0 + ty * 4 + r;
        if (gr >= M) continue;
        float2 o = make_float2(acc[r][0] + bias[tx * 2],
                               acc[r][1] + bias[tx * 2 + 1]);
        *(float2*)&C[(size_t)gr * 32 + tx * 2] = o;
    }
}

extern "C" void kernel_launch(void* const* d_in, const int* in_sizes, int n_in,
                              void* d_out, int out_size, void* d_ws, size_t ws_size,
                              hipStream_t stream) {
    const float* x     = (const float*)d_in[0];
    const int*   ei    = (const int*)  d_in[1];
    const float* W1a_l = (const float*)d_in[2];
    const float* b1a   = (const float*)d_in[3];
    const float* W1a_r = (const float*)d_in[4];
    const float* W1b_l = (const float*)d_in[5];
    const float* b1b   = (const float*)d_in[6];
    const float* W1b_r = (const float*)d_in[7];
    const float* W2a_l = (const float*)d_in[8];
    const float* b2a   = (const float*)d_in[9];
    const float* W2a_r = (const float*)d_in[10];
    const float* W2b_l = (const float*)d_in[11];
    const float* b2b   = (const float*)d_in[12];
    const float* W2b_r = (const float*)d_in[13];
    const float* Wlin  = (const float*)d_in[14];
    const float* blin  = (const float*)d_in[15];

    const int N = in_sizes[0] / 128;
    const int E = in_sizes[1] / 2;
    const int* src = ei;
    const int* dst = ei + E;
    const int nps = (N + NSLICE - 1) / NSLICE;    // nodes per slice
    const int nsb = (N + SCAN_NPB - 1) / SCAN_NPB; // scan blocks (25 @ N=50k)

    size_t o = 0;
    auto take = [&](size_t bytes) -> void* {
        void* p = (char*)d_ws + o;
        o += (bytes + 255) & ~(size_t)255;
        return p;
    };
    int*   cnt     = (int*)  take((size_t)N * 4);
    int*   row_ptr = (int*)  take((size_t)(N + 1) * 4);
    int*   cursor  = (int*)  take((size_t)N * 4);
    float* inv     = (float*)take((size_t)N * 4);
    int*   partial = (int*)  take((size_t)64 * 4);
    int*   adj     = (int*)  take((size_t)E * 4);
    float* t       = (float*)take((size_t)N * 64 * 4);
    float* u       = (float*)take((size_t)N * 64 * 4);
    float* hA      = (float*)take((size_t)N * 64 * 4);
    float* hB      = (float*)take((size_t)N * 64 * 4);
    (void)ws_size; (void)n_in; (void)out_size;

    const int mb = (N + 63) / 64;                 // mm blocks
    const int gb = (N * 64 + 255) / 256;          // gather blocks (wave/node)
    const int eb = (E + 255) / 256;

    // ---- build CSR ----
    const int fill_chunks = 96;                   // 768 blocks
    hipMemsetAsync(cnt, 0, (size_t)N * 4, stream);
    count_kernel<<<eb, 256, 0, stream>>>(dst, cnt, E);
    scan_partial<<<nsb, 256, 0, stream>>>(cnt, partial, N);
    scan_partial_scan<<<1, 64, 0, stream>>>(partial, nsb);
    scan_final<<<nsb, 256, 0, stream>>>(cnt, partial, row_ptr, cursor, inv, N);
    fill_sliced<<<NSLICE * fill_chunks, 256, 0, stream>>>(
        src, dst, cursor, adj, E, N, nps, fill_chunks);

    // ---- layer 1a: x[*,128] -> hA, relu ----
    mm_dual<128><<<mb, 256, 0, stream>>>(x, W1a_l, W1a_r, b1a, t, u, N);
    gather_fused<true><<<gb, 256, 0, stream>>>(t, adj, row_ptr, inv, u, hA, N);
    // ---- layer 1b: hA -> hB, relu ----
    mm_dual<64><<<mb, 256, 0, stream>>>(hA, W1b_l, W1b_r, b1b, t, u, N);
    gather_fused<true><<<gb, 256, 0, stream>>>(t, adj, row_ptr, inv, u, hB, N);
    // ---- layer 2a: hB -> hA, relu ----
    mm_dual<64><<<mb, 256, 0, stream>>>(hB, W2a_l, W2a_r, b2a, t, u, N);
    gather_fused<true><<<gb, 256, 0, stream>>>(t, adj, row_ptr, inv, u, hA, N);
    // ---- layer 2b: hA -> hB, no relu ----
    mm_dual<64><<<mb, 256, 0, stream>>>(hA, W2b_l, W2b_r, b2b, t, u, N);
    gather_fused<false><<<gb, 256, 0, stream>>>(t, adj, row_ptr, inv, u, hB, N);
    // ---- final linear ----
    mm_lin<<<mb, 256, 0, stream>>>(hB, Wlin, blin, (float*)d_out, N);
}

// Round 6
// 384.803 us; speedup vs baseline: 1.9920x; 1.2197x over previous
//
#include <hip/hip_runtime.h>
#include <hip/hip_fp16.h>

// ---------------------------------------------------------------------------
// GNNEncoder: 4x SAGEConv + linear. R5:
//  - t (neighbor transform) stored fp16, fp32 accumulate in gather: halves
//    the dominant L3 gather traffic (E x 256B -> E x 128B per layer).
//  - adj as ushort (N < 65536): halves fill scatter writes + gather adj reads.
//  - fill_chunks 96 -> 192 (occupancy 27% -> ~50%).
//  - gather: wave/node, 8 neighbor-groups x 8 lanes x half8, shfl reduce.
//  - scan: 3-phase multi-block; count: plain atomics; fill: XCD-sliced.
// ---------------------------------------------------------------------------

#define NSLICE 8
#define SCAN_NPB 2048   // nodes per scan block (256 threads x 8)

__global__ void count_kernel(const int* __restrict__ dst, int* __restrict__ cnt, int E) {
    int e = blockIdx.x * blockDim.x + threadIdx.x;
    if (e < E) atomicAdd(&cnt[dst[e]], 1);
}

// phase 1: per-block sums of cnt
__global__ __launch_bounds__(256) void scan_partial(
    const int* __restrict__ cnt, int* __restrict__ partial, int N)
{
    __shared__ int red[256];
    const int base = blockIdx.x * SCAN_NPB + threadIdx.x * 8;
    int s = 0;
    #pragma unroll
    for (int k = 0; k < 8; ++k) {
        int i = base + k;
        if (i < N) s += cnt[i];
    }
    red[threadIdx.x] = s;
    __syncthreads();
    for (int off = 128; off > 0; off >>= 1) {
        if (threadIdx.x < off) red[threadIdx.x] += red[threadIdx.x + off];
        __syncthreads();
    }
    if (threadIdx.x == 0) partial[blockIdx.x] = red[0];
}

// phase 2: single wave exclusive-scans nb (<=64) partials in place
__global__ __launch_bounds__(64) void scan_partial_scan(int* __restrict__ partial, int nb)
{
    const int lane = threadIdx.x;
    int v = (lane < nb) ? partial[lane] : 0;
    int incl = v;
    #pragma unroll
    for (int off = 1; off < 64; off <<= 1) {
        int o = __shfl_up(incl, off);
        if (lane >= off) incl += o;
    }
    if (lane < nb) partial[lane] = incl - v;   // exclusive
}

// phase 3: local scan + offset -> row_ptr, cursor, inv; last node writes row_ptr[N]
__global__ __launch_bounds__(256) void scan_final(
    const int* __restrict__ cnt, const int* __restrict__ partial,
    int* __restrict__ row_ptr, int* __restrict__ cursor,
    float* __restrict__ inv, int N)
{
    __shared__ int sums[256];
    const int tid = threadIdx.x;
    const int base = blockIdx.x * SCAN_NPB + tid * 8;
    int c[8], p = 0;
    #pragma unroll
    for (int k = 0; k < 8; ++k) {
        int i = base + k;
        c[k] = (i < N) ? cnt[i] : 0;
        p += c[k];
    }
    sums[tid] = p;
    __syncthreads();
    for (int off = 1; off < 256; off <<= 1) {
        int v = (tid >= off) ? sums[tid - off] : 0;
        __syncthreads();
        sums[tid] += v;
        __syncthreads();
    }
    int run = partial[blockIdx.x] + ((tid > 0) ? sums[tid - 1] : 0);
    #pragma unroll
    for (int k = 0; k < 8; ++k) {
        int i = base + k;
        if (i < N) {
            row_ptr[i] = run;
            cursor[i]  = run;
            inv[i] = 1.0f / (float)(c[k] > 0 ? c[k] : 1);
            run += c[k];
            if (i == N - 1) row_ptr[N] = run;
        }
    }
}

// sliced fill: adj (ushort) writes + cursor atomics stay XCD-local
__global__ __launch_bounds__(256) void fill_sliced(
    const int* __restrict__ src, const int* __restrict__ dst,
    int* __restrict__ cursor, unsigned short* __restrict__ adj,
    int E, int N, int nps, int nchunk)
{
    const int slice = blockIdx.x & (NSLICE - 1);
    const int chunk = blockIdx.x / NSLICE;
    const int sbeg = slice * nps;
    const int send = min(sbeg + nps, N);
    const int lo = (int)((long long)E * chunk / nchunk);
    const int hi = (int)((long long)E * (chunk + 1) / nchunk);
    for (int e = lo + threadIdx.x; e < hi; e += 256) {
        int d = dst[e];
        if (d >= sbeg && d < send) {
            int pos = atomicAdd(&cursor[d], 1);
            adj[pos] = (unsigned short)src[e];
        }
    }
}

// pull aggregation fused with self-term: out = (relu)(u + inv * sum_j t[adj_j])
// one wave per node: 8 neighbor-groups x 8 dim-lanes, half8 (16B) per lane.
template<bool RELU>
__global__ __launch_bounds__(256) void gather_fused(
    const __half* __restrict__ t, const unsigned short* __restrict__ adj,
    const int* __restrict__ row_ptr, const float* __restrict__ inv,
    const float* __restrict__ u, float* __restrict__ out, int N)
{
    const int node = (blockIdx.x * 256 + threadIdx.x) >> 6;
    const int lane = threadIdx.x & 63;
    const int grp  = lane >> 3;          // 0..7: neighbor slot in the octet
    const int d0   = (lane & 7) * 8;     // dim offset (8 dims per lane)
    if (node >= N) return;
    const int beg = row_ptr[node], end = row_ptr[node + 1];
    float a[8] = {0.f, 0.f, 0.f, 0.f, 0.f, 0.f, 0.f, 0.f};
    int j = beg + grp;
    for (; j + 8 < end; j += 16) {       // 2x unrolled: j and j+8
        const int n0 = adj[j], n1 = adj[j + 8];
        const float4 p0 = *(const float4*)(t + (size_t)n0 * 64 + d0);
        const float4 p1 = *(const float4*)(t + (size_t)n1 * 64 + d0);
        const __half2* h0 = (const __half2*)&p0;
        const __half2* h1 = (const __half2*)&p1;
        #pragma unroll
        for (int k = 0; k < 4; ++k) {
            float2 f0 = __half22float2(h0[k]);
            float2 f1 = __half22float2(h1[k]);
            a[2 * k]     += f0.x + f1.x;
            a[2 * k + 1] += f0.y + f1.y;
        }
    }
    if (j < end) {
        const float4 p0 = *(const float4*)(t + (size_t)adj[j] * 64 + d0);
        const __half2* h0 = (const __half2*)&p0;
        #pragma unroll
        for (int k = 0; k < 4; ++k) {
            float2 f0 = __half22float2(h0[k]);
            a[2 * k]     += f0.x;
            a[2 * k + 1] += f0.y;
        }
    }
    // reduce across the 8 groups (lane bits 3,4,5)
    #pragma unroll
    for (int k = 0; k < 8; ++k) {
        a[k] += __shfl_xor(a[k], 8);
        a[k] += __shfl_xor(a[k], 16);
        a[k] += __shfl_xor(a[k], 32);
    }
    if (grp == 0) {
        const float vi = inv[node];
        const float4 u0 = *(const float4*)(u + (size_t)node * 64 + d0);
        const float4 u1 = *(const float4*)(u + (size_t)node * 64 + d0 + 4);
        float4 o0, o1;
        o0.x = u0.x + a[0] * vi; o0.y = u0.y + a[1] * vi;
        o0.z = u0.z + a[2] * vi; o0.w = u0.w + a[3] * vi;
        o1.x = u1.x + a[4] * vi; o1.y = u1.y + a[5] * vi;
        o1.z = u1.z + a[6] * vi; o1.w = u1.w + a[7] * vi;
        if (RELU) {
            o0.x = fmaxf(o0.x, 0.f); o0.y = fmaxf(o0.y, 0.f);
            o0.z = fmaxf(o0.z, 0.f); o0.w = fmaxf(o0.w, 0.f);
            o1.x = fmaxf(o1.x, 0.f); o1.y = fmaxf(o1.y, 0.f);
            o1.z = fmaxf(o1.z, 0.f); o1.w = fmaxf(o1.w, 0.f);
        }
        *(float4*)(out + (size_t)node * 64 + d0)     = o0;
        *(float4*)(out + (size_t)node * 64 + d0 + 4) = o1;
    }
}

// T[M,64] (fp16) = A[M,K]@Wl ; U[M,64] (fp32) = A[M,K]@Wr + b
template<int K>
__global__ __launch_bounds__(256) void mm_dual(
    const float* __restrict__ A, const float* __restrict__ Wl,
    const float* __restrict__ Wr, const float* __restrict__ bias,
    __half* __restrict__ T, float* __restrict__ U, int M)
{
    __shared__ float As[64][68];
    __shared__ float Wls[64 * 64];
    __shared__ float Wrs[64 * 64];
    const int tid  = threadIdx.x;
    const int row0 = blockIdx.x * 64;
    const int tx = tid & 15, ty = tid >> 4;
    float accT[4][4] = {{0.f}}, accU[4][4] = {{0.f}};

    for (int kc = 0; kc < K; kc += 64) {
        for (int i = tid * 4; i < 64 * 64; i += 1024) {
            int r = i >> 6, c = i & 63;
            int gr = row0 + r;
            float4 v = make_float4(0.f, 0.f, 0.f, 0.f);
            if (gr < M) v = *(const float4*)&A[(size_t)gr * K + kc + c];
            *(float4*)&As[r][c] = v;
        }
        for (int i = tid * 4; i < 64 * 64; i += 1024) {
            *(float4*)&Wls[i] = *(const float4*)&Wl[kc * 64 + i];
            *(float4*)&Wrs[i] = *(const float4*)&Wr[kc * 64 + i];
        }
        __syncthreads();
        #pragma unroll 4
        for (int kk = 0; kk < 64; ++kk) {
            float a[4];
            #pragma unroll
            for (int r = 0; r < 4; ++r) a[r] = As[ty * 4 + r][kk];
            float bl[4], br[4];
            #pragma unroll
            for (int c = 0; c < 4; ++c) {
                bl[c] = Wls[kk * 64 + tx * 4 + c];
                br[c] = Wrs[kk * 64 + tx * 4 + c];
            }
            #pragma unroll
            for (int r = 0; r < 4; ++r)
                #pragma unroll
                for (int c = 0; c < 4; ++c) {
                    accT[r][c] += a[r] * bl[c];
                    accU[r][c] += a[r] * br[c];
                }
        }
        __syncthreads();
    }

    const float4 bv = *(const float4*)&bias[tx * 4];
    #pragma unroll
    for (int r = 0; r < 4; ++r) {
        int gr = row0 + ty * 4 + r;
        if (gr >= M) continue;
        union { int2 v; __half2 h[2]; } up;
        up.h[0] = __floats2half2_rn(accT[r][0], accT[r][1]);
        up.h[1] = __floats2half2_rn(accT[r][2], accT[r][3]);
        *(int2*)&T[(size_t)gr * 64 + tx * 4] = up.v;
        *(float4*)&U[(size_t)gr * 64 + tx * 4] =
            make_float4(accU[r][0] + bv.x, accU[r][1] + bv.y,
                        accU[r][2] + bv.z, accU[r][3] + bv.w);
    }
}

// final linear: C[M,32] = A[M,64]@W + b
__global__ __launch_bounds__(256) void mm_lin(
    const float* __restrict__ A, const float* __restrict__ W,
    const float* __restrict__ bias, float* __restrict__ C, int M)
{
    __shared__ float As[64][68];
    __shared__ float Ws[64 * 32];
    const int tid  = threadIdx.x;
    const int row0 = blockIdx.x * 64;

    for (int i = tid * 4; i < 64 * 32; i += 1024) {
        *(float4*)&Ws[i] = *(const float4*)&W[i];
    }
    for (int i = tid * 4; i < 64 * 64; i += 1024) {
        int r = i >> 6, c = i & 63;
        int gr = row0 + r;
        float4 v = make_float4(0.f, 0.f, 0.f, 0.f);
        if (gr < M) v = *(const float4*)&A[(size_t)gr * 64 + c];
        *(float4*)&As[r][c] = v;
    }
    __syncthreads();

    const int tx = tid & 15, ty = tid >> 4;
    float acc[4][2] = {{0.f}};
    #pragma unroll 4
    for (int kk = 0; kk < 64; ++kk) {
        float a[4];
        #pragma unroll
        for (int r = 0; r < 4; ++r) a[r] = As[ty * 4 + r][kk];
        float b0 = Ws[kk * 32 + tx * 2];
        float b1 = Ws[kk * 32 + tx * 2 + 1];
        #pragma unroll
        for (int r = 0; r < 4; ++r) {
            acc[r][0] += a[r] * b0;
            acc[r][1] += a[r] * b1;
        }
    }
    #pragma unroll
    for (int r = 0; r < 4; ++r) {
        int gr = row0 + ty * 4 + r;
        if (gr >= M) continue;
        float2 o = make_float2(acc[r][0] + bias[tx * 2],
                               acc[r][1] + bias[tx * 2 + 1]);
        *(float2*)&C[(size_t)gr * 32 + tx * 2] = o;
    }
}

extern "C" void kernel_launch(void* const* d_in, const int* in_sizes, int n_in,
                              void* d_out, int out_size, void* d_ws, size_t ws_size,
                              hipStream_t stream) {
    const float* x     = (const float*)d_in[0];
    const int*   ei    = (const int*)  d_in[1];
    const float* W1a_l = (const float*)d_in[2];
    const float* b1a   = (const float*)d_in[3];
    const float* W1a_r = (const float*)d_in[4];
    const float* W1b_l = (const float*)d_in[5];
    const float* b1b   = (const float*)d_in[6];
    const float* W1b_r = (const float*)d_in[7];
    const float* W2a_l = (const float*)d_in[8];
    const float* b2a   = (const float*)d_in[9];
    const float* W2a_r = (const float*)d_in[10];
    const float* W2b_l = (const float*)d_in[11];
    const float* b2b   = (const float*)d_in[12];
    const float* W2b_r = (const float*)d_in[13];
    const float* Wlin  = (const float*)d_in[14];
    const float* blin  = (const float*)d_in[15];

    const int N = in_sizes[0] / 128;
    const int E = in_sizes[1] / 2;
    const int* src = ei;
    const int* dst = ei + E;
    const int nps = (N + NSLICE - 1) / NSLICE;     // nodes per slice
    const int nsb = (N + SCAN_NPB - 1) / SCAN_NPB; // scan blocks (25 @ N=50k)

    size_t o = 0;
    auto take = [&](size_t bytes) -> void* {
        void* p = (char*)d_ws + o;
        o += (bytes + 255) & ~(size_t)255;
        return p;
    };
    int*            cnt     = (int*)   take((size_t)N * 4);
    int*            row_ptr = (int*)   take((size_t)(N + 1) * 4);
    int*            cursor  = (int*)   take((size_t)N * 4);
    float*          inv     = (float*) take((size_t)N * 4);
    int*            partial = (int*)   take((size_t)64 * 4);
    unsigned short* adj     = (unsigned short*)take((size_t)E * 2);
    __half*         t       = (__half*)take((size_t)N * 64 * 2);
    float*          u       = (float*) take((size_t)N * 64 * 4);
    float*          hA      = (float*) take((size_t)N * 64 * 4);
    float*          hB      = (float*) take((size_t)N * 64 * 4);
    (void)ws_size; (void)n_in; (void)out_size;

    const int mb = (N + 63) / 64;                 // mm blocks
    const int gb = (N * 64 + 255) / 256;          // gather blocks (wave/node)
    const int eb = (E + 255) / 256;

    // ---- build CSR ----
    const int fill_chunks = 192;                  // 1536 blocks
    hipMemsetAsync(cnt, 0, (size_t)N * 4, stream);
    count_kernel<<<eb, 256, 0, stream>>>(dst, cnt, E);
    scan_partial<<<nsb, 256, 0, stream>>>(cnt, partial, N);
    scan_partial_scan<<<1, 64, 0, stream>>>(partial, nsb);
    scan_final<<<nsb, 256, 0, stream>>>(cnt, partial, row_ptr, cursor, inv, N);
    fill_sliced<<<NSLICE * fill_chunks, 256, 0, stream>>>(
        src, dst, cursor, adj, E, N, nps, fill_chunks);

    // ---- layer 1a: x[*,128] -> hA, relu ----
    mm_dual<128><<<mb, 256, 0, stream>>>(x, W1a_l, W1a_r, b1a, t, u, N);
    gather_fused<true><<<gb, 256, 0, stream>>>(t, adj, row_ptr, inv, u, hA, N);
    // ---- layer 1b: hA -> hB, relu ----
    mm_dual<64><<<mb, 256, 0, stream>>>(hA, W1b_l, W1b_r, b1b, t, u, N);
    gather_fused<true><<<gb, 256, 0, stream>>>(t, adj, row_ptr, inv, u, hB, N);
    // ---- layer 2a: hB -> hA, relu ----
    mm_dual<64><<<mb, 256, 0, stream>>>(hB, W2a_l, W2a_r, b2a, t, u, N);
    gather_fused<true><<<gb, 256, 0, stream>>>(t, adj, row_ptr, inv, u, hA, N);
    // ---- layer 2b: hA -> hB, no relu ----
    mm_dual<64><<<mb, 256, 0, stream>>>(hA, W2b_l, W2b_r, b2b, t, u, N);
    gather_fused<false><<<gb, 256, 0, stream>>>(t, adj, row_ptr, inv, u, hB, N);
    // ---- final linear ----
    mm_lin<<<mb, 256, 0, stream>>>(hB, Wlin, blin, (float*)d_out, N);
}